// Round 1
// baseline (319.267 us; speedup 1.0000x reference)
//
#include <hip/hip_runtime.h>
#include <cstdint>
#include <cstddef>

#define BATCH 8192
#define IN_F 1024
#define OUT_F 1024
#define NSPL 9               // 1 base channel + 8 spline basis channels
#define KDIM (IN_F * NSPL)   // 9216

#define BM 256
#define BN 128
#define BK 64
#define NTILE (KDIM / BK)    // 144

typedef __bf16 bf16x8 __attribute__((ext_vector_type(8)));
typedef float f32x4 __attribute__((ext_vector_type(4)));

// async global->LDS, 16B/lane; LDS dest is wave-uniform base + lane*16 (linear!)
__device__ __forceinline__ void g2l16(const void* g, void* l) {
  __builtin_amdgcn_global_load_lds(
      (__attribute__((address_space(1))) void*)(g),
      (__attribute__((address_space(3))) void*)(l),
      16, 0, 0);
}

// raw barrier (no vmcnt(0) drain) + compiler-level memory fence both sides
__device__ __forceinline__ void barrier_raw() {
  asm volatile("" ::: "memory");
  __builtin_amdgcn_s_barrier();
  asm volatile("" ::: "memory");
}

// ---------------------------------------------------------------------------
// Kernel 1: combined weight Wt[o][i*9+r] bf16 (unchanged, proven).
// ---------------------------------------------------------------------------
__global__ void build_w(const float* __restrict__ bw, const float* __restrict__ sw,
                        const float* __restrict__ sc, __bf16* __restrict__ Wt) {
  __shared__ float s_sw[16 * 8 * 64];  // [i][r][oo] 32KB
  __shared__ float s_sc[16 * 64];      // [i][oo]     4KB
  __shared__ float s_bw[64 * 16];      // [oo][i]     4KB
  const int tid = threadIdx.x;
  const int o0 = (blockIdx.x & 15) * 64;
  const int i0 = (blockIdx.x >> 4) * 16;

#pragma unroll
  for (int it = 0; it < 32; ++it) {   // sw: 8192 floats
    const int t = it * 256 + tid;
    const int i = t >> 9, r = (t >> 6) & 7, oo = t & 63;
    s_sw[t] = sw[((size_t)(i0 + i) * 8 + r) * OUT_F + o0 + oo];
  }
#pragma unroll
  for (int it = 0; it < 4; ++it) {    // sc: 1024 floats
    const int t = it * 256 + tid;
    const int i = t >> 6, oo = t & 63;
    s_sc[t] = sc[(size_t)(i0 + i) * OUT_F + o0 + oo];
  }
#pragma unroll
  for (int it = 0; it < 4; ++it) {    // bw: 1024 floats
    const int t = it * 256 + tid;
    const int oo = t >> 4, ii = t & 15;
    s_bw[t] = bw[(size_t)(o0 + oo) * IN_F + i0 + ii];
  }
  __syncthreads();

  const int oo = tid >> 2;
  const int isub = (tid & 3) * 4;
#pragma unroll
  for (int is = 0; is < 4; ++is) {
    const int i = isub + is;
    __bf16* dst = Wt + (size_t)(o0 + oo) * KDIM + (size_t)(i0 + i) * NSPL;
    dst[0] = (__bf16)s_bw[oo * 16 + i];
    const float scal = s_sc[i * 64 + oo];
#pragma unroll
    for (int r = 0; r < 8; ++r)
      dst[1 + r] = (__bf16)(s_sw[i * 512 + r * 64 + oo] * scal);
  }
}

// ---------------------------------------------------------------------------
// Kernel 2: augmented activations A[b][i*9+r] bf16 (unchanged, proven).
// ---------------------------------------------------------------------------
__global__ void build_a(const float* __restrict__ x, __bf16* __restrict__ A) {
  __shared__ __align__(16) __bf16 rowbuf[KDIM];  // 18432 B
  const int b = blockIdx.x;
  const int tid = threadIdx.x;
#pragma unroll
  for (int c = 0; c < IN_F / 256; ++c) {
    const int i = c * 256 + tid;
    const float v = x[(size_t)b * IN_F + i];
    float w[NSPL];
#pragma unroll
    for (int r = 0; r < NSPL; ++r) w[r] = 0.f;
    w[0] = v / (1.f + __expf(-v));  // silu
    const float p = (v + 2.2f) * 2.5f;
    const int cell = (int)floorf(p);
    if (cell >= 0 && cell <= 10 && v < 2.2f) {
      const float t = p - (float)cell;
      const float t2 = t * t, t3 = t2 * t;
      const float omt = 1.f - t;
      const float b0 = (1.f / 6.f) * omt * omt * omt;
      const float b1 = (1.f / 6.f) * (3.f * t3 - 6.f * t2 + 4.f);
      const float b2 = (1.f / 6.f) * (-3.f * t3 + 3.f * t2 + 3.f * t + 1.f);
      const float b3 = (1.f / 6.f) * t3;
      const int j0 = cell - 3;
      if (j0 + 0 >= 0 && j0 + 0 <= 7) w[1 + j0 + 0] = b0;
      if (j0 + 1 >= 0 && j0 + 1 <= 7) w[1 + j0 + 1] = b1;
      if (j0 + 2 >= 0 && j0 + 2 <= 7) w[1 + j0 + 2] = b2;
      if (j0 + 3 >= 0 && j0 + 3 <= 7) w[1 + j0 + 3] = b3;
    }
    __bf16* d = rowbuf + (size_t)i * NSPL;
#pragma unroll
    for (int r = 0; r < NSPL; ++r) d[r] = (__bf16)w[r];
  }
  __syncthreads();
  const uint4* src = (const uint4*)rowbuf;
  uint4* dst = (uint4*)(A + (size_t)b * KDIM);
  for (int t = tid; t < KDIM * 2 / 16; t += 256)
    dst[t] = src[t];
}

// ---------------------------------------------------------------------------
// Kernel 3: GEMM out[8192][1024] = A[8192][9216] * Wt[1024][9216]^T
//
// Phase-split pipelined structure (T2+T3+T4+T5 port of the 8-phase template):
//   * 256x128 tile, BK=64, 512 threads = 8 waves (4M x 2N), 64x64 out/wave.
//   * Grid 32x8 = 256 blocks = 1/CU exactly (144KB LDS forces 1 block/CU).
//   * TRIPLE-buffered LDS: compute buf t%3 while tile t+2 streams into
//     buf (t+2)%3 -> loads have ~2 tile-computes to land; per-tile wait is
//     counted s_waitcnt vmcnt(6) (t+2's 6 loads stay in flight), vmcnt(0)
//     only at the final tile. Raw s_barrier (no implicit drain).
//   * T2 XOR swizzle on [row][64] bf16 tiles: 16B-unit ^= (row&7).
//     global_load_lds writes linearly, so the swizzle is applied as
//     inverse-permuted GLOBAL source (rule #21) + permuted ds_read address.
//     Post-swizzle fragment reads are 2-way (free); pre-swizzle they'd be
//     16-way (lanes 0-15 at stride 128B).
//   * 2 phases/tile (one per k-half): {8x ds_read_b128 || 3x g2l16 ->
//     barrier -> setprio(1) -> 16 MFMA -> setprio(0) -> barrier}.
//   * XCD swizzle: each XCD owns one n-panel (B-panel 2.4MB L2-resident).
// ---------------------------------------------------------------------------
__global__ __launch_bounds__(512, 2) void gemm_bt(const __bf16* __restrict__ A,
                                                  const __bf16* __restrict__ W,
                                                  float* __restrict__ out) {
  __shared__ __align__(16) __bf16 As[3][BM * BK];  // 3 x 32KB = 96KB
  __shared__ __align__(16) __bf16 Bs[3][BN * BK];  // 3 x 16KB = 48KB

  const int tid = threadIdx.x;
  const int wv = tid >> 6;     // 0..7
  const int lane = tid & 63;

  // bijective XCD swizzle: 256 blocks, 8 XCDs -> XCD x gets n-tile x, all m
  const int bid = blockIdx.x;
  const int swz = (bid & 7) * 32 + (bid >> 3);
  const int m0 = (swz & 31) * BM;
  const int n0 = (swz >> 5) * BN;

  const int wr = wv >> 1;      // wave m index 0..3 (64-row slice)
  const int wc = wv & 1;       // wave n index 0..1 (64-col slice)

  // ---- staging addressing (pre-swizzled source) ----
  // wave wv stages A rows wv*32+{0,8,16,24}+srow, B rows wv*16+{0,8}+srow.
  // lane: srow = l>>3 (== row&7), linear 16B-unit = l&7, source unit = ^srow.
  const int srow = lane >> 3;
  const int usrc = (lane & 7) ^ srow;
  const __bf16* gA = A + (size_t)(m0 + wv * 32 + srow) * KDIM + usrc * 8;
  const __bf16* gB = W + (size_t)(n0 + wv * 16 + srow) * KDIM + usrc * 8;

#define STAGE3_FIRST(q, tt)                                          \
  do {                                                               \
    const size_t ko = (size_t)(tt) * BK;                             \
    g2l16(gA + ko,                      &As[q][(wv * 32 + 0) * BK]); \
    g2l16(gA + ko + 8 * (size_t)KDIM,   &As[q][(wv * 32 + 8) * BK]); \
    g2l16(gB + ko,                      &Bs[q][(wv * 16 + 0) * BK]); \
  } while (0)
#define STAGE3_SECOND(q, tt)                                          \
  do {                                                                \
    const size_t ko = (size_t)(tt) * BK;                              \
    g2l16(gA + ko + 16 * (size_t)KDIM, &As[q][(wv * 32 + 16) * BK]);  \
    g2l16(gA + ko + 24 * (size_t)KDIM, &As[q][(wv * 32 + 24) * BK]);  \
    g2l16(gB + ko + 8 * (size_t)KDIM,  &Bs[q][(wv * 16 + 8) * BK]);   \
  } while (0)

  // ---- fragment read addressing (swizzled) ----
  const int mrow = lane & 15;
  const int quad = lane >> 4;
  int aoff[4], boff[4];
#pragma unroll
  for (int mt = 0; mt < 4; ++mt) aoff[mt] = (wr * 64 + mt * 16 + mrow) * BK;
#pragma unroll
  for (int nt = 0; nt < 4; ++nt) boff[nt] = (wc * 64 + nt * 16 + mrow) * BK;
  // k-half h, quad q -> logical 16B-unit (h*4+q), physical = ^ (row&7), *8 elems
  const int colx0 = ((quad) ^ (mrow & 7)) * 8;
  const int colx1 = ((4 + quad) ^ (mrow & 7)) * 8;

  f32x4 acc[4][4];
  const f32x4 zero = {0.f, 0.f, 0.f, 0.f};
#pragma unroll
  for (int mt = 0; mt < 4; ++mt)
#pragma unroll
    for (int nt = 0; nt < 4; ++nt) acc[mt][nt] = zero;

  // ---- prologue: stage tiles 0,1 -> bufs 0,1 (12 loads); wait tile 0 ----
  STAGE3_FIRST(0, 0);
  STAGE3_SECOND(0, 0);
  STAGE3_FIRST(1, 1);
  STAGE3_SECOND(1, 1);
  asm volatile("s_waitcnt vmcnt(6)" ::: "memory");  // tile 0 landed (own wave)
  barrier_raw();                                    // all waves' tile 0 visible

  int q = 0;
  for (int t = 0; t < NTILE; ++t) {
    const int qp = (q == 0) ? 2 : q - 1;  // (q+2)%3 : buffer freed by tile t-1

    // ================= phase 0 (k-half 0) =================
    bf16x8 a0[4], b0[4];
#pragma unroll
    for (int mt = 0; mt < 4; ++mt) a0[mt] = *(const bf16x8*)(&As[q][aoff[mt] + colx0]);
#pragma unroll
    for (int nt = 0; nt < 4; ++nt) b0[nt] = *(const bf16x8*)(&Bs[q][boff[nt] + colx0]);
    if (t + 2 < NTILE) STAGE3_FIRST(qp, t + 2);
    barrier_raw();
    __builtin_amdgcn_s_setprio(1);
#pragma unroll
    for (int mt = 0; mt < 4; ++mt)
#pragma unroll
      for (int nt = 0; nt < 4; ++nt)
        acc[mt][nt] = __builtin_amdgcn_mfma_f32_16x16x32_bf16(a0[mt], b0[nt],
                                                              acc[mt][nt], 0, 0, 0);
    __builtin_amdgcn_s_setprio(0);
    barrier_raw();

    // ================= phase 1 (k-half 1) =================
    bf16x8 a1[4], b1[4];
#pragma unroll
    for (int mt = 0; mt < 4; ++mt) a1[mt] = *(const bf16x8*)(&As[q][aoff[mt] + colx1]);
#pragma unroll
    for (int nt = 0; nt < 4; ++nt) b1[nt] = *(const bf16x8*)(&Bs[q][boff[nt] + colx1]);
    if (t + 2 < NTILE) {
      STAGE3_SECOND(qp, t + 2);
      // outstanding <= 12 (t+1's 6 + t+2's 6); wait oldest 6 -> tile t+1 ready,
      // t+2's 6 stay in flight across the barrier (counted, never drained)
      asm volatile("s_waitcnt vmcnt(6)" ::: "memory");
    } else {
      // no t+2 staged: only t+1's loads remain -> full drain (epilogue of pipe)
      asm volatile("s_waitcnt vmcnt(0)" ::: "memory");
    }
    barrier_raw();
    __builtin_amdgcn_s_setprio(1);
#pragma unroll
    for (int mt = 0; mt < 4; ++mt)
#pragma unroll
      for (int nt = 0; nt < 4; ++nt)
        acc[mt][nt] = __builtin_amdgcn_mfma_f32_16x16x32_bf16(a1[mt], b1[nt],
                                                              acc[mt][nt], 0, 0, 0);
    __builtin_amdgcn_s_setprio(0);
    barrier_raw();

    q = (q == 2) ? 0 : q + 1;
  }

  // ---- epilogue: C/D layout col = lane&15, row = quad*4 + reg ----
#pragma unroll
  for (int mt = 0; mt < 4; ++mt) {
#pragma unroll
    for (int nt = 0; nt < 4; ++nt) {
      const int col = n0 + wc * 64 + nt * 16 + mrow;
      const int rbase = m0 + wr * 64 + mt * 16 + quad * 4;
#pragma unroll
      for (int r = 0; r < 4; ++r)
        out[(size_t)(rbase + r) * OUT_F + col] = acc[mt][nt][r];
    }
  }
#undef STAGE3_FIRST
#undef STAGE3_SECOND
}

// ---------------------------------------------------------------------------
extern "C" void kernel_launch(void* const* d_in, const int* in_sizes, int n_in,
                              void* d_out, int out_size, void* d_ws, size_t ws_size,
                              hipStream_t stream) {
  const float* x  = (const float*)d_in[0];
  // d_in[1] = grid: uniform linspace, folded into closed-form basis (unused)
  const float* bw = (const float*)d_in[2];  // [OUT_F, IN_F]
  const float* sw = (const float*)d_in[3];  // [IN_F, 8, OUT_F]
  const float* sc = (const float*)d_in[4];  // [IN_F, OUT_F]
  float* out = (float*)d_out;

  __bf16* Wt = (__bf16*)d_ws;                                    // [OUT_F][KDIM] 18.9 MB
  __bf16* Ab = (__bf16*)((char*)d_ws +
                         (size_t)OUT_F * KDIM * sizeof(__bf16)); // [BATCH][KDIM] 151 MB

  build_w<<<1024, 256, 0, stream>>>(bw, sw, sc, Wt);
  build_a<<<BATCH, 256, 0, stream>>>(x, Ab);
  gemm_bt<<<(BATCH / BM) * (OUT_F / BN), 512, 0, stream>>>(Ab, Wt, out);
}

// Round 3
// 289.514 us; speedup vs baseline: 1.1028x; 1.1028x over previous
//
#include <hip/hip_runtime.h>
#include <cstdint>
#include <cstddef>

#define BATCH 8192
#define IN_F 1024
#define OUT_F 1024
#define NSPL 9               // 1 base channel + 8 spline basis channels
#define KDIM (IN_F * NSPL)   // 9216

#define BM 256
#define BN 128
#define BK 64
#define NTILE (KDIM / BK)    // 144

typedef __bf16 bf16x8 __attribute__((ext_vector_type(8)));
typedef float f32x4 __attribute__((ext_vector_type(4)));

// async global->LDS, 16B/lane; LDS dest is wave-uniform base + lane*16 (linear!)
__device__ __forceinline__ void g2l16(const void* g, void* l) {
  __builtin_amdgcn_global_load_lds(
      (__attribute__((address_space(1))) void*)(g),
      (__attribute__((address_space(3))) void*)(l),
      16, 0, 0);
}

// raw barrier (no vmcnt(0) drain) + compiler-level memory fence both sides
__device__ __forceinline__ void barrier_raw() {
  asm volatile("" ::: "memory");
  __builtin_amdgcn_s_barrier();
  asm volatile("" ::: "memory");
}

// ---------------------------------------------------------------------------
// Kernel 1: combined weight Wt[o][i*9+r] bf16 (unchanged, proven).
// ---------------------------------------------------------------------------
__global__ void build_w(const float* __restrict__ bw, const float* __restrict__ sw,
                        const float* __restrict__ sc, __bf16* __restrict__ Wt) {
  __shared__ float s_sw[16 * 8 * 64];  // [i][r][oo] 32KB
  __shared__ float s_sc[16 * 64];      // [i][oo]     4KB
  __shared__ float s_bw[64 * 16];      // [oo][i]     4KB
  const int tid = threadIdx.x;
  const int o0 = (blockIdx.x & 15) * 64;
  const int i0 = (blockIdx.x >> 4) * 16;

#pragma unroll
  for (int it = 0; it < 32; ++it) {   // sw: 8192 floats
    const int t = it * 256 + tid;
    const int i = t >> 9, r = (t >> 6) & 7, oo = t & 63;
    s_sw[t] = sw[((size_t)(i0 + i) * 8 + r) * OUT_F + o0 + oo];
  }
#pragma unroll
  for (int it = 0; it < 4; ++it) {    // sc: 1024 floats
    const int t = it * 256 + tid;
    const int i = t >> 6, oo = t & 63;
    s_sc[t] = sc[(size_t)(i0 + i) * OUT_F + o0 + oo];
  }
#pragma unroll
  for (int it = 0; it < 4; ++it) {    // bw: 1024 floats
    const int t = it * 256 + tid;
    const int oo = t >> 4, ii = t & 15;
    s_bw[t] = bw[(size_t)(o0 + oo) * IN_F + i0 + ii];
  }
  __syncthreads();

  const int oo = tid >> 2;
  const int isub = (tid & 3) * 4;
#pragma unroll
  for (int is = 0; is < 4; ++is) {
    const int i = isub + is;
    __bf16* dst = Wt + (size_t)(o0 + oo) * KDIM + (size_t)(i0 + i) * NSPL;
    dst[0] = (__bf16)s_bw[oo * 16 + i];
    const float scal = s_sc[i * 64 + oo];
#pragma unroll
    for (int r = 0; r < 8; ++r)
      dst[1 + r] = (__bf16)(s_sw[i * 512 + r * 64 + oo] * scal);
  }
}

// ---------------------------------------------------------------------------
// Kernel 2: augmented activations A[b][i*9+r] bf16.
//   * 2 rows/block, 128 threads/row, 8 features/thread (float4 x2 input).
//   * basis scatter as fully-unrolled branchless selects (ALL indices static,
//     rule #20: no runtime-indexed local arrays).
//   * 72 bf16 packed in registers, written as 9x ds_write_b128 at 144B stride,
//     then coalesced uint4 copy-out.
// ---------------------------------------------------------------------------
__global__ __launch_bounds__(256) void build_a(const float* __restrict__ x,
                                               __bf16* __restrict__ A) {
  __shared__ __align__(16) __bf16 rowbuf[2 * KDIM];  // 36,864 B -> 4 blocks/CU
  const int tid = threadIdx.x;
  const int r2 = tid >> 7;             // row within block (0..1)
  const int tr = tid & 127;            // thread within row
  const size_t b = (size_t)blockIdx.x * 2 + r2;

  const float4* xp = (const float4*)(x + b * IN_F + (size_t)tr * 8);
  const float4 v0 = xp[0], v1 = xp[1];
  const float vv[8] = {v0.x, v0.y, v0.z, v0.w, v1.x, v1.y, v1.z, v1.w};

  union HB { __bf16 h[72]; uint4 q[9]; } hb;

#pragma unroll
  for (int f = 0; f < 8; ++f) {
    const float v = vv[f];
    const float s0 = v / (1.f + __expf(-v));  // silu
    // uniform cubic B-spline, knots t_j = -2.2 + 0.4j (j=0..11)
    const float p = (v + 2.2f) * 2.5f;
    const int cell = (int)floorf(p);
    const bool ok = (cell >= 0) && (cell <= 10) && (v < 2.2f);
    const float gate = ok ? (1.f / 6.f) : 0.f;
    const float t = p - (float)cell;     // in [0,1) for all finite v
    const float t2 = t * t, t3 = t2 * t;
    const float omt = 1.f - t;
    const float c0 = gate * omt * omt * omt;
    const float c1 = gate * (3.f * t3 - 6.f * t2 + 4.f);
    const float c2 = gate * (-3.f * t3 + 3.f * t2 + 3.f * t + 1.f);
    const float c3 = gate * t3;
    const int j0 = cell - 3;
    hb.h[f * 9 + 0] = (__bf16)s0;
#pragma unroll
    for (int r = 0; r < 8; ++r) {      // branchless scatter, static indices
      const int d = r - j0;
      float val = (d == 0) ? c0 : 0.f;
      val = (d == 1) ? c1 : val;
      val = (d == 2) ? c2 : val;
      val = (d == 3) ? c3 : val;
      hb.h[f * 9 + 1 + r] = (__bf16)val;
    }
  }

  uint4* ldst = (uint4*)(rowbuf + (size_t)r2 * KDIM) + (size_t)tr * 9;
#pragma unroll
  for (int k = 0; k < 9; ++k) ldst[k] = hb.q[k];
  __syncthreads();

  const uint4* src = (const uint4*)rowbuf;
  uint4* dst = (uint4*)(A + (size_t)blockIdx.x * 2 * KDIM);
#pragma unroll
  for (int it = 0; it < 9; ++it)       // 2304 uint4 / 256 threads
    dst[it * 256 + tid] = src[it * 256 + tid];
}

// ---------------------------------------------------------------------------
// Kernel 3: GEMM out[8192][1024] = A[8192][9216] * Wt[1024][9216]^T
//
// Structure from round 1 (T2 swizzle verified: bank conflicts = 0;
// triple-buffered counted-vmcnt pipeline). ONE change vs round 1: XCD m-band
// block mapping. XCD x owns m-tiles [4x,4x+4) x ALL 8 n-tiles (its 32 CUs,
// 1 block/CU). A is then read by exactly one XCD (151 MB total) and the
// per-K-step XCD working set (4x32KB A + 8x16KB B = 256KB) is L2-resident.
// W (19 MB, shared by all XCDs) stays L3-hot.
// ---------------------------------------------------------------------------
__global__ __launch_bounds__(512, 2) void gemm_bt(const __bf16* __restrict__ A,
                                                  const __bf16* __restrict__ W,
                                                  float* __restrict__ out) {
  __shared__ __align__(16) __bf16 As[3][BM * BK];  // 3 x 32KB = 96KB
  __shared__ __align__(16) __bf16 Bs[3][BN * BK];  // 3 x 16KB = 48KB

  const int tid = threadIdx.x;
  const int wv = tid >> 6;     // 0..7
  const int lane = tid & 63;

  // XCD m-band mapping (bijective): xcd = bid&7 owns m-tiles 4*xcd..4*xcd+3
  const int bid = blockIdx.x;
  const int xcd = bid & 7;
  const int j = bid >> 3;                    // 0..31 within XCD
  const int m0 = (xcd * 4 + (j & 3)) * BM;
  const int n0 = (j >> 2) * BN;

  const int wr = wv >> 1;      // wave m index 0..3 (64-row slice)
  const int wc = wv & 1;       // wave n index 0..1 (64-col slice)

  // ---- staging addressing (pre-swizzled source, rule #21) ----
  const int srow = lane >> 3;
  const int usrc = (lane & 7) ^ srow;
  const __bf16* gA = A + (size_t)(m0 + wv * 32 + srow) * KDIM + usrc * 8;
  const __bf16* gB = W + (size_t)(n0 + wv * 16 + srow) * KDIM + usrc * 8;

#define STAGE3_FIRST(q, tt)                                          \
  do {                                                               \
    const size_t ko = (size_t)(tt) * BK;                             \
    g2l16(gA + ko,                      &As[q][(wv * 32 + 0) * BK]); \
    g2l16(gA + ko + 8 * (size_t)KDIM,   &As[q][(wv * 32 + 8) * BK]); \
    g2l16(gB + ko,                      &Bs[q][(wv * 16 + 0) * BK]); \
  } while (0)
#define STAGE3_SECOND(q, tt)                                          \
  do {                                                                \
    const size_t ko = (size_t)(tt) * BK;                              \
    g2l16(gA + ko + 16 * (size_t)KDIM, &As[q][(wv * 32 + 16) * BK]);  \
    g2l16(gA + ko + 24 * (size_t)KDIM, &As[q][(wv * 32 + 24) * BK]);  \
    g2l16(gB + ko + 8 * (size_t)KDIM,  &Bs[q][(wv * 16 + 8) * BK]);   \
  } while (0)

  // ---- fragment read addressing (swizzled) ----
  const int mrow = lane & 15;
  const int quad = lane >> 4;
  int aoff[4], boff[4];
#pragma unroll
  for (int mt = 0; mt < 4; ++mt) aoff[mt] = (wr * 64 + mt * 16 + mrow) * BK;
#pragma unroll
  for (int nt = 0; nt < 4; ++nt) boff[nt] = (wc * 64 + nt * 16 + mrow) * BK;
  const int colx0 = ((quad) ^ (mrow & 7)) * 8;
  const int colx1 = ((4 + quad) ^ (mrow & 7)) * 8;

  f32x4 acc[4][4];
  const f32x4 zero = {0.f, 0.f, 0.f, 0.f};
#pragma unroll
  for (int mt = 0; mt < 4; ++mt)
#pragma unroll
    for (int nt = 0; nt < 4; ++nt) acc[mt][nt] = zero;

  // ---- prologue: stage tiles 0,1 -> bufs 0,1; wait tile 0 ----
  STAGE3_FIRST(0, 0);
  STAGE3_SECOND(0, 0);
  STAGE3_FIRST(1, 1);
  STAGE3_SECOND(1, 1);
  asm volatile("s_waitcnt vmcnt(6)" ::: "memory");  // tile 0 landed (own wave)
  barrier_raw();                                    // all waves' tile 0 visible

  int q = 0;
  for (int t = 0; t < NTILE; ++t) {
    const int qp = (q == 0) ? 2 : q - 1;  // buffer freed by tile t-1

    // ================= phase 0 (k-half 0) =================
    bf16x8 a0[4], b0[4];
#pragma unroll
    for (int mt = 0; mt < 4; ++mt) a0[mt] = *(const bf16x8*)(&As[q][aoff[mt] + colx0]);
#pragma unroll
    for (int nt = 0; nt < 4; ++nt) b0[nt] = *(const bf16x8*)(&Bs[q][boff[nt] + colx0]);
    if (t + 2 < NTILE) STAGE3_FIRST(qp, t + 2);
    barrier_raw();
    __builtin_amdgcn_s_setprio(1);
#pragma unroll
    for (int mt = 0; mt < 4; ++mt)
#pragma unroll
      for (int nt = 0; nt < 4; ++nt)
        acc[mt][nt] = __builtin_amdgcn_mfma_f32_16x16x32_bf16(a0[mt], b0[nt],
                                                              acc[mt][nt], 0, 0, 0);
    __builtin_amdgcn_s_setprio(0);
    barrier_raw();

    // ================= phase 1 (k-half 1) =================
    bf16x8 a1[4], b1[4];
#pragma unroll
    for (int mt = 0; mt < 4; ++mt) a1[mt] = *(const bf16x8*)(&As[q][aoff[mt] + colx1]);
#pragma unroll
    for (int nt = 0; nt < 4; ++nt) b1[nt] = *(const bf16x8*)(&Bs[q][boff[nt] + colx1]);
    if (t + 2 < NTILE) {
      STAGE3_SECOND(qp, t + 2);
      // oldest 6 = tile t+1 ready; t+2's 6 stay in flight across the barrier
      asm volatile("s_waitcnt vmcnt(6)" ::: "memory");
    } else {
      asm volatile("s_waitcnt vmcnt(0)" ::: "memory");  // pipeline epilogue
    }
    barrier_raw();
    __builtin_amdgcn_s_setprio(1);
#pragma unroll
    for (int mt = 0; mt < 4; ++mt)
#pragma unroll
      for (int nt = 0; nt < 4; ++nt)
        acc[mt][nt] = __builtin_amdgcn_mfma_f32_16x16x32_bf16(a1[mt], b1[nt],
                                                              acc[mt][nt], 0, 0, 0);
    __builtin_amdgcn_s_setprio(0);
    barrier_raw();

    q = (q == 2) ? 0 : q + 1;
  }

  // ---- epilogue: C/D layout col = lane&15, row = quad*4 + reg ----
#pragma unroll
  for (int mt = 0; mt < 4; ++mt) {
#pragma unroll
    for (int nt = 0; nt < 4; ++nt) {
      const int col = n0 + wc * 64 + nt * 16 + mrow;
      const int rbase = m0 + wr * 64 + mt * 16 + quad * 4;
#pragma unroll
      for (int r = 0; r < 4; ++r)
        out[(size_t)(rbase + r) * OUT_F + col] = acc[mt][nt][r];
    }
  }
#undef STAGE3_FIRST
#undef STAGE3_SECOND
}

// ---------------------------------------------------------------------------
extern "C" void kernel_launch(void* const* d_in, const int* in_sizes, int n_in,
                              void* d_out, int out_size, void* d_ws, size_t ws_size,
                              hipStream_t stream) {
  const float* x  = (const float*)d_in[0];
  // d_in[1] = grid: uniform linspace, folded into closed-form basis (unused)
  const float* bw = (const float*)d_in[2];  // [OUT_F, IN_F]
  const float* sw = (const float*)d_in[3];  // [IN_F, 8, OUT_F]
  const float* sc = (const float*)d_in[4];  // [IN_F, OUT_F]
  float* out = (float*)d_out;

  __bf16* Wt = (__bf16*)d_ws;                                    // [OUT_F][KDIM] 18.9 MB
  __bf16* Ab = (__bf16*)((char*)d_ws +
                         (size_t)OUT_F * KDIM * sizeof(__bf16)); // [BATCH][KDIM] 151 MB

  build_w<<<1024, 256, 0, stream>>>(bw, sw, sc, Wt);
  build_a<<<BATCH / 2, 256, 0, stream>>>(x, Ab);
  gemm_bt<<<(BATCH / BM) * (OUT_F / BN), 512, 0, stream>>>(Ab, Wt, out);
}